// Round 1
// 435.456 us; speedup vs baseline: 1.0376x; 1.0376x over previous
//
#include <hip/hip_runtime.h>
#include <stdint.h>

#define T_TOK 2048
#define KTOP  2
#define NEXP  8
#define HDIM  1024
#define IDIM  2816

#define NPAIR 4096

// ---- new path (bf16 transposed weights) ----
#define BM        128
#define MAX_TILES 40                // 8 XCDs x 5 tiles (swizzle relies on 40%8==0)
#define NPP       (NPAIR + BM)      // 4224
#define BN2       128               // gate/up N tile
#define BK2       32
#define BN3       64                // down N tile
#define BK3       64

// ---- fallback (round-1) path ----
#define R1BM   256
#define R1T    24
#define R1NPP  (NPAIR + R1BM)       // 4352
#define R1BN2  128
#define R1BK2  32
#define R1BKp2 40
#define R1BN3  64
#define R1BK3  64
#define R1BKp3 72

typedef __attribute__((ext_vector_type(8))) short short8;
typedef __attribute__((ext_vector_type(4))) float floatx4;

__device__ __forceinline__ unsigned short f2bf(float f) {
  unsigned int u = __float_as_uint(f);
  u += 0x7fffu + ((u >> 16) & 1u);   // round-to-nearest-even
  return (unsigned short)(u >> 16);
}

// HW packed f32->bf16 (RNE, matches f2bf): dst = {lo=bf16(a), hi=bf16(b)}
__device__ __forceinline__ unsigned int pkbf(float a, float b) {
  unsigned int r;
  asm volatile("v_cvt_pk_bf16_f32 %0, %1, %2" : "=v"(r) : "v"(a), "v"(b));
  return r;
}

__device__ __forceinline__ void glds16(const unsigned short* g, unsigned short* l) {
  __builtin_amdgcn_global_load_lds(
      (const __attribute__((address_space(1))) unsigned int*)g,
      (__attribute__((address_space(3))) unsigned int*)l, 16, 0, 0);
}

// XCD-chunked tile swizzle: HW round-robins linear block id over 8 XCDs
// (id%8 == bx%8 since gridDim.x==40 and 40%8==0). Map so XCD k services
// contiguous tiles 5k..5k+4 -> one XCD touches ~1 expert's weight panels,
// which then stay resident in its private 4MB L2 across all n-tiles.
__device__ __forceinline__ int xcd_tile(int bx0) {
  return (bx0 & 7) * (MAX_TILES / 8) + (bx0 >> 3);
}

// ---------------------------------------------------------------- setup ----
__global__ void setup_kernel(const int* __restrict__ idx,
                             const float* __restrict__ vals,
                             int* __restrict__ hdr,
                             int* __restrict__ stok,
                             float* __restrict__ sw, int bm) {
  __shared__ int cnt[NEXP];
  __shared__ int off[NEXP];
  int tid = threadIdx.x;
  if (tid < NEXP) cnt[tid] = 0;
  __syncthreads();
  for (int p = tid; p < NPAIR; p += blockDim.x) atomicAdd(&cnt[idx[p]], 1);
  __syncthreads();
  if (tid == 0) {
    int s = 0, nt = 0;
    for (int e = 0; e < NEXP; ++e) {
      off[e] = s;
      int n = cnt[e];
      for (int t0 = 0; t0 < n; t0 += bm) {
        hdr[nt] = e;
        hdr[64 + nt] = s + t0;
        hdr[128 + nt] = s + n;
        nt++;
      }
      s += n;
    }
    for (; nt < 64; ++nt) hdr[nt] = -1;
  }
  __syncthreads();
  for (int p = tid; p < NPAIR; p += blockDim.x) {
    int e = idx[p];
    int pos = atomicAdd(&off[e], 1);
    stok[pos] = p / KTOP;
    sw[pos] = vals[p];
  }
}

// --------------------------------------------------------------- gather ----
__global__ void gather_kernel(const float* __restrict__ hidden,
                              const int* __restrict__ stok,
                              unsigned short* __restrict__ Xs) {
  int p = blockIdx.x;
  int t = stok[p];
  const float4* src = reinterpret_cast<const float4*>(hidden + (size_t)t * HDIM);
  float4 v = src[threadIdx.x];
  uint2 q;
  q.x = pkbf(v.x, v.y);
  q.y = pkbf(v.z, v.w);
  *reinterpret_cast<uint2*>(Xs + (size_t)p * HDIM + threadIdx.x * 4) = q;
}

// ----------------------------------------------- weight convert+transpose --
// fp32 [e][M][N] -> bf16 [e][N][M].  z (+zoff): 0=wg, 1=wu, 2=wd.
__global__ __launch_bounds__(256) void convert_kernel(
    const float* __restrict__ wg, const float* __restrict__ wu,
    const float* __restrict__ wd, unsigned short* __restrict__ wgT,
    unsigned short* __restrict__ wuT, unsigned short* __restrict__ wdT,
    int zoff) {
  __shared__ float ls[64][65];
  int z = blockIdx.z + zoff;
  int e = blockIdx.y;
  int M = (z == 2) ? IDIM : HDIM;
  int N = (z == 2) ? HDIM : IDIM;
  const float* src = (z == 0 ? wg : z == 1 ? wu : wd) + (size_t)e * M * N;
  unsigned short* dst = (z == 0 ? wgT : z == 1 ? wuT : wdT) + (size_t)e * M * N;
  int ntx = N >> 6;
  int n0 = (blockIdx.x % ntx) << 6;
  int m0 = (blockIdx.x / ntx) << 6;
  int t = threadIdx.x;
  int rr = t >> 4, cc = (t & 15) * 4;
#pragma unroll
  for (int i = 0; i < 4; ++i) {
    int r = rr + i * 16;
    float4 v = *reinterpret_cast<const float4*>(src + (size_t)(m0 + r) * N + n0 + cc);
    ls[r][cc] = v.x; ls[r][cc + 1] = v.y; ls[r][cc + 2] = v.z; ls[r][cc + 3] = v.w;
  }
  __syncthreads();
  int mc = (t & 7) * 8, nn = t >> 3;   // 8 lanes per output row, 16B/lane
#pragma unroll
  for (int i = 0; i < 2; ++i) {
    int n = nn + i * 32;
    uint4 q;
    q.x = pkbf(ls[mc][n],     ls[mc + 1][n]);
    q.y = pkbf(ls[mc + 2][n], ls[mc + 3][n]);
    q.z = pkbf(ls[mc + 4][n], ls[mc + 5][n]);
    q.w = pkbf(ls[mc + 6][n], ls[mc + 7][n]);
    *reinterpret_cast<uint4*>(dst + (size_t)(n0 + n) * M + m0 + mc) = q;
  }
}

// -------------------------------------------------- fused gate+up GEMM ----
// LDS k-chunk XOR swizzle: logical 16B chunk q of row r lives at physical
// chunk q ^ ((r>>1)&3)  (row stride 64B = 16 banks -> 2-way max aliasing).
// 2-phase pipeline: stage K-tile k+1 into buf^1 while computing buf; one
// __syncthreads (vmcnt+lgkm drain) per K-step.
__device__ __forceinline__ void stage_gu(
    const unsigned short* __restrict__ Xs, const unsigned short* __restrict__ wgb,
    const unsigned short* __restrict__ wub, int row0, int n0, int wave, int lr,
    int lk, int kb, unsigned short* As, unsigned short* Bg, unsigned short* Bu) {
#pragma unroll
  for (int it = 0; it < 2; ++it) {
    int c = wave * 2 + it;     // 0..7, 16 rows each
    glds16(Xs  + (size_t)(row0 + c * 16 + lr) * HDIM + kb + lk, &As[c * 512]);
    glds16(wgb + (size_t)(n0  + c * 16 + lr) * HDIM + kb + lk, &Bg[c * 512]);
    glds16(wub + (size_t)(n0  + c * 16 + lr) * HDIM + kb + lk, &Bu[c * 512]);
  }
}

__global__ __launch_bounds__(256, 2) void gateup_kernel(
    const unsigned short* __restrict__ Xs, const unsigned short* __restrict__ wgT,
    const unsigned short* __restrict__ wuT, const int* __restrict__ hdr,
    const float* __restrict__ sw_g, unsigned short* __restrict__ Act) {
  int bx = xcd_tile(blockIdx.x);       // m-tile, XCD-chunked
  int e = hdr[bx];
  if (e < 0) return;
  int row0 = hdr[64 + bx];
  int rowlim = hdr[128 + bx] - row0;
  int n0 = blockIdx.y * BN2;

  __shared__ __align__(16) unsigned short As[2][BM * BK2];
  __shared__ __align__(16) unsigned short Bg[2][BN2 * BK2];
  __shared__ __align__(16) unsigned short Bu[2][BN2 * BK2];
  __shared__ float sw[BM];

  int tid = threadIdx.x, lane = tid & 63, wave = tid >> 6;
  if (tid < BM) sw[tid] = sw_g[row0 + tid];

  const unsigned short* wgb = wgT + (size_t)e * IDIM * HDIM;  // [I][H] bf16
  const unsigned short* wub = wuT + (size_t)e * IDIM * HDIM;

  floatx4 accg[4][4], accu[4][4];
  floatx4 zz = {0.f, 0.f, 0.f, 0.f};
#pragma unroll
  for (int a = 0; a < 4; ++a)
#pragma unroll
    for (int b = 0; b < 4; ++b) { accg[a][b] = zz; accu[a][b] = zz; }

  int wm = (wave >> 1) * 64, wn = (wave & 1) * 64;
  int lr = lane >> 2;                        // row within 16-row chunk
  int lk = (((lane & 3) ^ ((lr >> 1) & 3)) * 8);   // swizzled global k-chunk
  int fr = lane & 15;
  int fq = (((lane >> 4) ^ ((fr >> 1) & 3)) * 8);  // swizzled read offset

  stage_gu(Xs, wgb, wub, row0, n0, wave, lr, lk, 0, As[0], Bg[0], Bu[0]);
  __syncthreads();

  int cur = 0;
  for (int kb = 0; kb < HDIM; kb += BK2) {
    if (kb + BK2 < HDIM)
      stage_gu(Xs, wgb, wub, row0, n0, wave, lr, lk, kb + BK2,
               As[cur ^ 1], Bg[cur ^ 1], Bu[cur ^ 1]);

    const unsigned short* Asc = As[cur];
    const unsigned short* Bgc = Bg[cur];
    const unsigned short* Buc = Bu[cur];
    short8 af[4], bg8[4], bu8[4];
#pragma unroll
    for (int x = 0; x < 4; ++x) {
      af[x]  = *reinterpret_cast<const short8*>(&Asc[(wm + x * 16 + fr) * BK2 + fq]);
      bg8[x] = *reinterpret_cast<const short8*>(&Bgc[(wn + x * 16 + fr) * BK2 + fq]);
      bu8[x] = *reinterpret_cast<const short8*>(&Buc[(wn + x * 16 + fr) * BK2 + fq]);
    }
#pragma unroll
    for (int tm = 0; tm < 4; ++tm)
#pragma unroll
      for (int tn = 0; tn < 4; ++tn) {
        accg[tm][tn] = __builtin_amdgcn_mfma_f32_16x16x32_bf16(af[tm], bg8[tn], accg[tm][tn], 0, 0, 0);
        accu[tm][tn] = __builtin_amdgcn_mfma_f32_16x16x32_bf16(af[tm], bu8[tn], accu[tm][tn], 0, 0, 0);
      }
    __syncthreads();   // drains this iter's prefetch vmcnt + all lgkm
    cur ^= 1;
  }

#pragma unroll
  for (int tm = 0; tm < 4; ++tm)
#pragma unroll
    for (int tn = 0; tn < 4; ++tn)
#pragma unroll
      for (int r = 0; r < 4; ++r) {
        int rl = wm + tm * 16 + (lane >> 4) * 4 + r;
        if (rl < rowlim) {
          int col = n0 + wn + tn * 16 + fr;
          float g = accg[tm][tn][r];
          float u = accu[tm][tn][r];
          float s = g / (1.f + __expf(-g));
          Act[(size_t)(row0 + rl) * IDIM + col] = f2bf(s * u * sw[rl]);
        }
      }
}

// ------------------------------------------------------------ down GEMM ----
// Row stride 128B = 32 banks: without swizzle every row aliases (16-way!).
// Swizzle: logical 16B chunk q of row r at physical q ^ (r&7).
__device__ __forceinline__ void stage_dn(
    const unsigned short* __restrict__ Act, const unsigned short* __restrict__ wdb,
    int row0, int n0, int wave, int lr8, int lk8, int kb,
    unsigned short* As, unsigned short* Bd) {
#pragma unroll
  for (int it = 0; it < 4; ++it) {
    int c = wave * 4 + it;     // 0..15, 8 rows each
    glds16(Act + (size_t)(row0 + c * 8 + lr8) * IDIM + kb + lk8, &As[c * 512]);
  }
#pragma unroll
  for (int it = 0; it < 2; ++it) {
    int c = wave * 2 + it;     // 0..7, 8 rows each
    glds16(wdb + (size_t)(n0 + c * 8 + lr8) * IDIM + kb + lk8, &Bd[c * 512]);
  }
}

__global__ __launch_bounds__(256, 3) void down_kernel(
    const unsigned short* __restrict__ Act, const unsigned short* __restrict__ wdT,
    const int* __restrict__ hdr, const int* __restrict__ stok,
    float* __restrict__ out) {
  int bx = xcd_tile(blockIdx.x);       // m-tile, XCD-chunked
  int e = hdr[bx];
  if (e < 0) return;
  int row0 = hdr[64 + bx];
  int rowlim = hdr[128 + bx] - row0;
  int n0 = blockIdx.y * BN3;

  __shared__ __align__(16) unsigned short As[2][BM * BK3];   // 2 x 128 x 64
  __shared__ __align__(16) unsigned short Bd[2][BN3 * BK3];  // 2 x 64 x 64
  __shared__ int stk[BM];

  int tid = threadIdx.x, lane = tid & 63, wave = tid >> 6;
  if (tid < BM) stk[tid] = stok[row0 + tid];

  const unsigned short* wdb = wdT + (size_t)e * HDIM * IDIM;  // [H][I] bf16

  floatx4 acc[4][2];
  floatx4 zz = {0.f, 0.f, 0.f, 0.f};
#pragma unroll
  for (int a = 0; a < 4; ++a) { acc[a][0] = zz; acc[a][1] = zz; }

  int wm = (wave >> 1) * 64, wn = (wave & 1) * 32;
  int lr8 = lane >> 3;                         // row within 8-row chunk
  int lk8 = (((lane & 7) ^ lr8) * 8);          // swizzled global k-chunk
  int fr = lane & 15;
  int fk = fr & 7;                             // swizzle key on read

  stage_dn(Act, wdb, row0, n0, wave, lr8, lk8, 0, As[0], Bd[0]);
  __syncthreads();

  int cur = 0;
  for (int kb = 0; kb < IDIM; kb += BK3) {   // 44 iters
    if (kb + BK3 < IDIM)
      stage_dn(Act, wdb, row0, n0, wave, lr8, lk8, kb + BK3, As[cur ^ 1], Bd[cur ^ 1]);

    const unsigned short* Asc = As[cur];
    const unsigned short* Bdc = Bd[cur];
#pragma unroll
    for (int ks = 0; ks < BK3; ks += 32) {
      int q8 = (ks >> 3) + (lane >> 4);        // logical chunk 0..7
      int fo = ((q8 ^ fk) * 8);                // physical offset
      short8 af[4], bd8[2];
#pragma unroll
      for (int x = 0; x < 4; ++x)
        af[x] = *reinterpret_cast<const short8*>(&Asc[(wm + x * 16 + fr) * BK3 + fo]);
#pragma unroll
      for (int x = 0; x < 2; ++x)
        bd8[x] = *reinterpret_cast<const short8*>(&Bdc[(wn + x * 16 + fr) * BK3 + fo]);
#pragma unroll
      for (int tm = 0; tm < 4; ++tm)
#pragma unroll
        for (int tn = 0; tn < 2; ++tn)
          acc[tm][tn] = __builtin_amdgcn_mfma_f32_16x16x32_bf16(af[tm], bd8[tn], acc[tm][tn], 0, 0, 0);
    }
    __syncthreads();
    cur ^= 1;
  }

#pragma unroll
  for (int tm = 0; tm < 4; ++tm)
#pragma unroll
    for (int tn = 0; tn < 2; ++tn)
#pragma unroll
      for (int r = 0; r < 4; ++r) {
        int rl = wm + tm * 16 + (lane >> 4) * 4 + r;
        if (rl < rowlim) {
          int col = n0 + wn + tn * 16 + fr;
          unsafeAtomicAdd(&out[(size_t)stk[rl] * HDIM + col], acc[tm][tn][r]);
        }
      }
}

// ======================== round-1 fallback kernels =========================
__global__ __launch_bounds__(512, 2) void gateup_fb(
    const unsigned short* __restrict__ Xs, const float* __restrict__ wg,
    const float* __restrict__ wu, const int* __restrict__ hdr,
    const float* __restrict__ sw_g, unsigned short* __restrict__ Act) {
  int by = blockIdx.y;
  int e = hdr[by];
  if (e < 0) return;
  int row0 = hdr[64 + by];
  int row_end = hdr[128 + by];
  int n0 = blockIdx.x * R1BN2;

  __shared__ __align__(16) unsigned short As[R1BM * R1BKp2];
  __shared__ __align__(16) unsigned short Bg[R1BN2 * R1BKp2];
  __shared__ __align__(16) unsigned short Bu[R1BN2 * R1BKp2];
  __shared__ float sw[R1BM];

  int tid = threadIdx.x, lane = tid & 63, wave = tid >> 6;
  if (tid < R1BM) sw[tid] = sw_g[row0 + tid];

  const float* wgb = wg + (size_t)e * HDIM * IDIM;
  const float* wub = wu + (size_t)e * HDIM * IDIM;

  floatx4 accg[4][4], accu[4][4];
  floatx4 zz = {0.f, 0.f, 0.f, 0.f};
#pragma unroll
  for (int a = 0; a < 4; ++a)
#pragma unroll
    for (int b = 0; b < 4; ++b) { accg[a][b] = zz; accu[a][b] = zz; }

  int wm = (wave >> 1) * 64, wn = (wave & 1) * 64;

  for (int kb = 0; kb < HDIM; kb += R1BK2) {
    __syncthreads();
#pragma unroll
    for (int it = 0; it < 2; ++it) {
      int cc = wave * 2 + it;
      int m = cc * 16 + (lane >> 2);
      int k = (lane & 3) * 8;
      uint4 v = *reinterpret_cast<const uint4*>(Xs + (size_t)(row0 + m) * HDIM + kb + k);
      *reinterpret_cast<uint4*>(&As[m * R1BKp2 + k]) = v;
    }
#pragma unroll
    for (int it = 0; it < 2; ++it) {
      int cc = wave * 2 + it;
      const float* wb = (cc & 8) ? wub : wgb;
      unsigned short* Bs = (cc & 8) ? Bu : Bg;
      int r = cc & 7;
      int kblk = r >> 1, nh = r & 1;
      int n = nh * 64 + lane;
      int k = kblk * 8;
      const float* src = wb + (size_t)(kb + k) * IDIM + n0 + n;
      uint4 q;
      q.x = f2bf(src[0])                | ((unsigned)f2bf(src[(size_t)IDIM])     << 16);
      q.y = f2bf(src[2 * (size_t)IDIM]) | ((unsigned)f2bf(src[3 * (size_t)IDIM]) << 16);
      q.z = f2bf(src[4 * (size_t)IDIM]) | ((unsigned)f2bf(src[5 * (size_t)IDIM]) << 16);
      q.w = f2bf(src[6 * (size_t)IDIM]) | ((unsigned)f2bf(src[7 * (size_t)IDIM]) << 16);
      *reinterpret_cast<uint4*>(&Bs[n * R1BKp2 + k]) = q;
    }
    __syncthreads();

    int krd = (lane >> 4) * 8;
    short8 af[4], bgf[4], buf_[4];
#pragma unroll
    for (int tm = 0; tm < 4; ++tm)
      af[tm] = *reinterpret_cast<const short8*>(&As[(wm + tm * 16 + (lane & 15)) * R1BKp2 + krd]);
#pragma unroll
    for (int tn = 0; tn < 4; ++tn) {
      bgf[tn]  = *reinterpret_cast<const short8*>(&Bg[(wn + tn * 16 + (lane & 15)) * R1BKp2 + krd]);
      buf_[tn] = *reinterpret_cast<const short8*>(&Bu[(wn + tn * 16 + (lane & 15)) * R1BKp2 + krd]);
    }
#pragma unroll
    for (int tm = 0; tm < 4; ++tm)
#pragma unroll
      for (int tn = 0; tn < 4; ++tn) {
        accg[tm][tn] = __builtin_amdgcn_mfma_f32_16x16x32_bf16(af[tm], bgf[tn], accg[tm][tn], 0, 0, 0);
        accu[tm][tn] = __builtin_amdgcn_mfma_f32_16x16x32_bf16(af[tm], buf_[tn], accu[tm][tn], 0, 0, 0);
      }
  }

  int rowlim = row_end - row0;
#pragma unroll
  for (int tm = 0; tm < 4; ++tm)
#pragma unroll
    for (int tn = 0; tn < 4; ++tn)
#pragma unroll
      for (int r = 0; r < 4; ++r) {
        int rl = wm + tm * 16 + (lane >> 4) * 4 + r;
        if (rl < rowlim) {
          int col = n0 + wn + tn * 16 + (lane & 15);
          float g = accg[tm][tn][r];
          float u = accu[tm][tn][r];
          float s = g / (1.f + __expf(-g));
          Act[(size_t)(row0 + rl) * IDIM + col] = f2bf(s * u * sw[rl]);
        }
      }
}

__global__ __launch_bounds__(512, 2) void down_fb(
    const unsigned short* __restrict__ Act, const float* __restrict__ wd,
    const int* __restrict__ hdr, const int* __restrict__ stok,
    float* __restrict__ out) {
  int by = blockIdx.y;
  int e = hdr[by];
  if (e < 0) return;
  int row0 = hdr[64 + by];
  int row_end = hdr[128 + by];
  int n0 = blockIdx.x * R1BN3;

  __shared__ __align__(16) unsigned short As[R1BM * R1BKp3];
  __shared__ __align__(16) unsigned short Bd[R1BN3 * R1BKp3];
  __shared__ int stk[R1BM];

  int tid = threadIdx.x, lane = tid & 63, wave = tid >> 6;
  if (tid < R1BM) stk[tid] = stok[row0 + tid];

  const float* wdb = wd + (size_t)e * IDIM * HDIM;

  floatx4 acc[4][2];
  floatx4 zz = {0.f, 0.f, 0.f, 0.f};
#pragma unroll
  for (int a = 0; a < 4; ++a) { acc[a][0] = zz; acc[a][1] = zz; }

  int wm = (wave >> 1) * 64, wn = (wave & 1) * 32;

  for (int kb = 0; kb < IDIM; kb += R1BK3) {
    __syncthreads();
#pragma unroll
    for (int it = 0; it < 4; ++it) {
      int cc = wave * 4 + it;
      int m = cc * 8 + (lane >> 3);
      int k = (lane & 7) * 8;
      uint4 v = *reinterpret_cast<const uint4*>(Act + (size_t)(row0 + m) * IDIM + kb + k);
      *reinterpret_cast<uint4*>(&As[m * R1BKp3 + k]) = v;
    }
    {
      int n = lane;
      int k = wave * 8;
      const float* src = wdb + (size_t)(kb + k) * HDIM + n0 + n;
      uint4 q;
      q.x = f2bf(src[0])        | ((unsigned)f2bf(src[HDIM])     << 16);
      q.y = f2bf(src[2 * HDIM]) | ((unsigned)f2bf(src[3 * HDIM]) << 16);
      q.z = f2bf(src[4 * HDIM]) | ((unsigned)f2bf(src[5 * HDIM]) << 16);
      q.w = f2bf(src[6 * HDIM]) | ((unsigned)f2bf(src[7 * HDIM]) << 16);
      *reinterpret_cast<uint4*>(&Bd[n * R1BKp3 + k]) = q;
    }
    __syncthreads();

#pragma unroll
    for (int ks = 0; ks < R1BK3; ks += 32) {
      int krd = ks + (lane >> 4) * 8;
      short8 af[4], bdf[2];
#pragma unroll
      for (int tm = 0; tm < 4; ++tm)
        af[tm] = *reinterpret_cast<const short8*>(&As[(wm + tm * 16 + (lane & 15)) * R1BKp3 + krd]);
#pragma unroll
      for (int tn = 0; tn < 2; ++tn)
        bdf[tn] = *reinterpret_cast<const short8*>(&Bd[(wn + tn * 16 + (lane & 15)) * R1BKp3 + krd]);
#pragma unroll
      for (int tm = 0; tm < 4; ++tm)
#pragma unroll
        for (int tn = 0; tn < 2; ++tn)
          acc[tm][tn] = __builtin_amdgcn_mfma_f32_16x16x32_bf16(af[tm], bdf[tn], acc[tm][tn], 0, 0, 0);
    }
  }

  int rowlim = row_end - row0;
#pragma unroll
  for (int tm = 0; tm < 4; ++tm)
#pragma unroll
    for (int tn = 0; tn < 2; ++tn)
#pragma unroll
      for (int r = 0; r < 4; ++r) {
        int rl = wm + tm * 16 + (lane >> 4) * 4 + r;
        if (rl < rowlim) {
          int col = n0 + wn + tn * 16 + (lane & 15);
          unsafeAtomicAdd(&out[(size_t)stk[rl] * HDIM + col], acc[tm][tn][r]);
        }
      }
}

// ---------------------------------------------------------------- launch ----
extern "C" void kernel_launch(void* const* d_in, const int* in_sizes, int n_in,
                              void* d_out, int out_size, void* d_ws, size_t ws_size,
                              hipStream_t stream) {
  const float* hidden = (const float*)d_in[0];
  const int* idx = (const int*)d_in[1];
  const float* vals = (const float*)d_in[2];
  const float* wg = (const float*)d_in[3];
  const float* wu = (const float*)d_in[4];
  const float* wd = (const float*)d_in[5];
  float* out = (float*)d_out;
  char* ws = (char*)d_ws;

  hipMemsetAsync(d_out, 0, (size_t)out_size * sizeof(float), stream);

  const size_t OFF_STOK = 4096;
  const size_t OFF_SW   = OFF_STOK + (size_t)NPP * 4;
  const size_t OFF_XS   = 65536;
  const size_t OFF_ACT  = OFF_XS + (size_t)NPP * HDIM * 2;
  const size_t OFF_WG   = OFF_ACT + (size_t)NPP * IDIM * 2;
  const size_t WSZ      = (size_t)NEXP * HDIM * IDIM * 2;   // 46.1 MB each
  const size_t OFF_WU   = OFF_WG + WSZ;
  const size_t NEED     = OFF_WU + WSZ;  // wdT aliases wgT

  if (ws_size >= NEED) {
    int* hdr = (int*)ws;
    int* stok = (int*)(ws + OFF_STOK);
    float* sw = (float*)(ws + OFF_SW);
    unsigned short* Xs  = (unsigned short*)(ws + OFF_XS);
    unsigned short* Act = (unsigned short*)(ws + OFF_ACT);
    unsigned short* wgT = (unsigned short*)(ws + OFF_WG);
    unsigned short* wuT = (unsigned short*)(ws + OFF_WU);
    unsigned short* wdT = wgT;  // alias: wd converted after gateup consumed wgT

    setup_kernel<<<1, 1024, 0, stream>>>(idx, vals, hdr, stok, sw, BM);
    convert_kernel<<<dim3(704, NEXP, 2), 256, 0, stream>>>(wg, wu, wd, wgT, wuT, wdT, 0);
    gather_kernel<<<NPAIR, 256, 0, stream>>>(hidden, stok, Xs);
    gateup_kernel<<<dim3(MAX_TILES, IDIM / BN2), 256, 0, stream>>>(Xs, wgT, wuT, hdr, sw, Act);
    convert_kernel<<<dim3(704, NEXP, 1), 256, 0, stream>>>(wg, wu, wd, wgT, wuT, wdT, 2);
    down_kernel<<<dim3(MAX_TILES, HDIM / BN3), 256, 0, stream>>>(Act, wdT, hdr, stok, out);
  } else {
    int* hdr = (int*)ws;
    int* stok = (int*)(ws + 4096);
    float* sw = (float*)(ws + 4096 + (size_t)R1NPP * 4);
    unsigned short* Xs  = (unsigned short*)(ws + 65536);
    unsigned short* Act = (unsigned short*)(ws + 65536 + (size_t)R1NPP * HDIM * 2);

    setup_kernel<<<1, 1024, 0, stream>>>(idx, vals, hdr, stok, sw, R1BM);
    gather_kernel<<<NPAIR, 256, 0, stream>>>(hidden, stok, Xs);
    gateup_fb<<<dim3(IDIM / R1BN2, R1T), 512, 0, stream>>>(Xs, wg, wu, hdr, sw, Act);
    down_fb<<<dim3(HDIM / R1BN3, R1T), 512, 0, stream>>>(Act, wd, hdr, stok, out);
  }
}

// Round 2
// 420.294 us; speedup vs baseline: 1.0751x; 1.0361x over previous
//
#include <hip/hip_runtime.h>
#include <stdint.h>

#define T_TOK 2048
#define KTOP  2
#define NEXP  8
#define HDIM  1024
#define IDIM  2816

#define NPAIR 4096

// ---- bf16 transposed-weight path ----
#define BM        128
#define MAX_TILES 40                // 8 XCDs x 5 tiles (swizzle relies on 40%8==0)
#define NPP       (NPAIR + BM)      // 4224
#define BN2       128               // gate/up N tile
#define BK2       32
#define BN3       64                // down N tile
#define BK3       64
#define GUB       (MAX_TILES * (IDIM / BN2))   // 880 gateup blocks
#define CVB       ((IDIM / 64) * (HDIM / 64) * NEXP)  // 5632 conv-z2 blocks

// ---- fallback (round-1) path ----
#define R1BM   256
#define R1T    24
#define R1NPP  (NPAIR + R1BM)       // 4352
#define R1BN2  128
#define R1BK2  32
#define R1BKp2 40
#define R1BN3  64
#define R1BK3  64
#define R1BKp3 72

typedef __attribute__((ext_vector_type(8))) short short8;
typedef __attribute__((ext_vector_type(4))) float floatx4;

__device__ __forceinline__ unsigned short f2bf(float f) {
  unsigned int u = __float_as_uint(f);
  u += 0x7fffu + ((u >> 16) & 1u);   // round-to-nearest-even
  return (unsigned short)(u >> 16);
}

// HW packed f32->bf16 (RNE, matches f2bf): dst = {lo=bf16(a), hi=bf16(b)}
__device__ __forceinline__ unsigned int pkbf(float a, float b) {
  unsigned int r;
  asm volatile("v_cvt_pk_bf16_f32 %0, %1, %2" : "=v"(r) : "v"(a), "v"(b));
  return r;
}

__device__ __forceinline__ void glds16(const unsigned short* g, unsigned short* l) {
  __builtin_amdgcn_global_load_lds(
      (const __attribute__((address_space(1))) unsigned int*)g,
      (__attribute__((address_space(3))) unsigned int*)l, 16, 0, 0);
}

// XCD-chunked tile swizzle: with the m-tile index as the fast grid axis and
// gridDim.x (or the fused 1D decode modulus) a multiple of 8, XCD = mx % 8.
// Map so XCD k services contiguous tiles 5k..5k+4 -> one XCD touches ~1
// expert's weight panels, which stay resident in its private 4MB L2.
__device__ __forceinline__ int xcd_tile(int bx0) {
  return (bx0 & 7) * (MAX_TILES / 8) + (bx0 >> 3);
}

// ---------------------------------------------------------------- setup ----
__global__ void setup_kernel(const int* __restrict__ idx,
                             const float* __restrict__ vals,
                             int* __restrict__ hdr,
                             int* __restrict__ stok,
                             float* __restrict__ sw, int bm) {
  __shared__ int cnt[NEXP];
  __shared__ int off[NEXP];
  int tid = threadIdx.x;
  if (tid < NEXP) cnt[tid] = 0;
  __syncthreads();
  for (int p = tid; p < NPAIR; p += blockDim.x) atomicAdd(&cnt[idx[p]], 1);
  __syncthreads();
  if (tid == 0) {
    int s = 0, nt = 0;
    for (int e = 0; e < NEXP; ++e) {
      off[e] = s;
      int n = cnt[e];
      for (int t0 = 0; t0 < n; t0 += bm) {
        hdr[nt] = e;
        hdr[64 + nt] = s + t0;
        hdr[128 + nt] = s + n;
        nt++;
      }
      s += n;
    }
    for (; nt < 64; ++nt) hdr[nt] = -1;
  }
  __syncthreads();
  for (int p = tid; p < NPAIR; p += blockDim.x) {
    int e = idx[p];
    int pos = atomicAdd(&off[e], 1);
    stok[pos] = p / KTOP;
    sw[pos] = vals[p];
  }
}

// --------------------------------------------------------------- gather ----
__global__ void gather_kernel(const float* __restrict__ hidden,
                              const int* __restrict__ stok,
                              unsigned short* __restrict__ Xs) {
  int p = blockIdx.x;
  int t = stok[p];
  const float4* src = reinterpret_cast<const float4*>(hidden + (size_t)t * HDIM);
  float4 v = src[threadIdx.x];
  uint2 q;
  q.x = pkbf(v.x, v.y);
  q.y = pkbf(v.z, v.w);
  *reinterpret_cast<uint2*>(Xs + (size_t)p * HDIM + threadIdx.x * 4) = q;
}

// ----------------------------------------------- weight convert+transpose --
// fp32 [e][M][N] -> bf16 [e][N][M].  z (+zoff): 0=wg, 1=wu, 2=wd.
__global__ __launch_bounds__(256) void convert_kernel(
    const float* __restrict__ wg, const float* __restrict__ wu,
    const float* __restrict__ wd, unsigned short* __restrict__ wgT,
    unsigned short* __restrict__ wuT, unsigned short* __restrict__ wdT,
    int zoff) {
  __shared__ float ls[64][65];
  int z = blockIdx.z + zoff;
  int e = blockIdx.y;
  int M = (z == 2) ? IDIM : HDIM;
  int N = (z == 2) ? HDIM : IDIM;
  const float* src = (z == 0 ? wg : z == 1 ? wu : wd) + (size_t)e * M * N;
  unsigned short* dst = (z == 0 ? wgT : z == 1 ? wuT : wdT) + (size_t)e * M * N;
  int ntx = N >> 6;
  int n0 = (blockIdx.x % ntx) << 6;
  int m0 = (blockIdx.x / ntx) << 6;
  int t = threadIdx.x;
  int rr = t >> 4, cc = (t & 15) * 4;
#pragma unroll
  for (int i = 0; i < 4; ++i) {
    int r = rr + i * 16;
    float4 v = *reinterpret_cast<const float4*>(src + (size_t)(m0 + r) * N + n0 + cc);
    ls[r][cc] = v.x; ls[r][cc + 1] = v.y; ls[r][cc + 2] = v.z; ls[r][cc + 3] = v.w;
  }
  __syncthreads();
  int mc = (t & 7) * 8, nn = t >> 3;   // 8 lanes per output row, 16B/lane
#pragma unroll
  for (int i = 0; i < 2; ++i) {
    int n = nn + i * 32;
    uint4 q;
    q.x = pkbf(ls[mc][n],     ls[mc + 1][n]);
    q.y = pkbf(ls[mc + 2][n], ls[mc + 3][n]);
    q.z = pkbf(ls[mc + 4][n], ls[mc + 5][n]);
    q.w = pkbf(ls[mc + 6][n], ls[mc + 7][n]);
    *reinterpret_cast<uint4*>(dst + (size_t)(n0 + n) * M + m0 + mc) = q;
  }
}

// -------------------------------------------------- fused gate+up GEMM ----
// 1-phase staging (round-0 structure: 24.5KB LDS -> 4 blocks/CU, cross-block
// overlap hides the stage drain) + XCD tile swizzle (L2-local weight panels).
// Optional tail blocks (blockIdx.x >= GUB) perform the wd fp32->bf16
// transpose-convert, backfilling CU stall cycles during the GEMM.
// LDS k-chunk XOR swizzle: logical 16B chunk q of row r lives at physical
// chunk q ^ ((r>>1)&3)  (row stride 64B = 16 banks -> 2-way max aliasing).
__global__ __launch_bounds__(256, 2) void gateup_kernel(
    const unsigned short* __restrict__ Xs, const unsigned short* __restrict__ wgT,
    const unsigned short* __restrict__ wuT, const int* __restrict__ hdr,
    const float* __restrict__ sw_g, unsigned short* __restrict__ Act,
    const float* __restrict__ wd, unsigned short* __restrict__ wdT) {
  __shared__ __align__(16) char smem[25088];

  if (blockIdx.x >= GUB) {
    // ---- convert z=2 tail block: wd fp32 [e][I][H] -> wdT bf16 [e][H][I] ----
    int cb = blockIdx.x - GUB;           // 0..CVB-1
    int e = cb / ((IDIM / 64) * (HDIM / 64));
    int bq = cb % ((IDIM / 64) * (HDIM / 64));
    const int ntx = HDIM >> 6;           // 16
    int n0 = (bq % ntx) << 6;
    int m0 = (bq / ntx) << 6;
    const float* src = wd + (size_t)e * IDIM * HDIM;
    unsigned short* dst = wdT + (size_t)e * IDIM * HDIM;
    float (*ls)[65] = reinterpret_cast<float(*)[65]>(smem);
    int t = threadIdx.x;
    int rr = t >> 4, cc = (t & 15) * 4;
#pragma unroll
    for (int i = 0; i < 4; ++i) {
      int r = rr + i * 16;
      float4 v = *reinterpret_cast<const float4*>(src + (size_t)(m0 + r) * HDIM + n0 + cc);
      ls[r][cc] = v.x; ls[r][cc + 1] = v.y; ls[r][cc + 2] = v.z; ls[r][cc + 3] = v.w;
    }
    __syncthreads();
    int mc = (t & 7) * 8, nn = t >> 3;
#pragma unroll
    for (int i = 0; i < 2; ++i) {
      int n = nn + i * 32;
      uint4 q;
      q.x = pkbf(ls[mc][n],     ls[mc + 1][n]);
      q.y = pkbf(ls[mc + 2][n], ls[mc + 3][n]);
      q.z = pkbf(ls[mc + 4][n], ls[mc + 5][n]);
      q.w = pkbf(ls[mc + 6][n], ls[mc + 7][n]);
      *reinterpret_cast<uint4*>(dst + (size_t)(n0 + n) * IDIM + m0 + mc) = q;
    }
    return;
  }

  // ---- gateup block ----
  int mx = blockIdx.x % MAX_TILES;     // fast axis -> XCD = mx % 8
  int ny = blockIdx.x / MAX_TILES;
  int bx = xcd_tile(mx);
  int e = hdr[bx];
  if (e < 0) return;
  int row0 = hdr[64 + bx];
  int rowlim = hdr[128 + bx] - row0;
  int n0 = ny * BN2;

  unsigned short* As = reinterpret_cast<unsigned short*>(smem);          // 8KB
  unsigned short* Bg = reinterpret_cast<unsigned short*>(smem + 8192);   // 8KB
  unsigned short* Bu = reinterpret_cast<unsigned short*>(smem + 16384);  // 8KB
  float* sw = reinterpret_cast<float*>(smem + 24576);                    // 512B

  int tid = threadIdx.x, lane = tid & 63, wave = tid >> 6;
  if (tid < BM) sw[tid] = sw_g[row0 + tid];

  const unsigned short* wgb = wgT + (size_t)e * IDIM * HDIM;  // [I][H] bf16
  const unsigned short* wub = wuT + (size_t)e * IDIM * HDIM;

  floatx4 accg[4][4], accu[4][4];
  floatx4 zz = {0.f, 0.f, 0.f, 0.f};
#pragma unroll
  for (int a = 0; a < 4; ++a)
#pragma unroll
    for (int b = 0; b < 4; ++b) { accg[a][b] = zz; accu[a][b] = zz; }

  int wm = (wave >> 1) * 64, wn = (wave & 1) * 64;
  int lr = lane >> 2;                        // row within 16-row chunk
  int lk = (((lane & 3) ^ ((lr >> 1) & 3)) * 8);   // swizzled global k-chunk
  int fr = lane & 15;
  int fq = (((lane >> 4) ^ ((fr >> 1) & 3)) * 8);  // swizzled read offset

  for (int kb = 0; kb < HDIM; kb += BK2) {
#pragma unroll
    for (int it = 0; it < 2; ++it) {
      int c = wave * 2 + it;     // 0..7, 16 rows each
      glds16(Xs  + (size_t)(row0 + c * 16 + lr) * HDIM + kb + lk, &As[c * 512]);
      glds16(wgb + (size_t)(n0  + c * 16 + lr) * HDIM + kb + lk, &Bg[c * 512]);
      glds16(wub + (size_t)(n0  + c * 16 + lr) * HDIM + kb + lk, &Bu[c * 512]);
    }
    __syncthreads();

    short8 af[4], bg8[4], bu8[4];
#pragma unroll
    for (int x = 0; x < 4; ++x) {
      af[x]  = *reinterpret_cast<const short8*>(&As[(wm + x * 16 + fr) * BK2 + fq]);
      bg8[x] = *reinterpret_cast<const short8*>(&Bg[(wn + x * 16 + fr) * BK2 + fq]);
      bu8[x] = *reinterpret_cast<const short8*>(&Bu[(wn + x * 16 + fr) * BK2 + fq]);
    }
#pragma unroll
    for (int tm = 0; tm < 4; ++tm)
#pragma unroll
      for (int tn = 0; tn < 4; ++tn) {
        accg[tm][tn] = __builtin_amdgcn_mfma_f32_16x16x32_bf16(af[tm], bg8[tn], accg[tm][tn], 0, 0, 0);
        accu[tm][tn] = __builtin_amdgcn_mfma_f32_16x16x32_bf16(af[tm], bu8[tn], accu[tm][tn], 0, 0, 0);
      }
    __syncthreads();
  }

#pragma unroll
  for (int tm = 0; tm < 4; ++tm)
#pragma unroll
    for (int tn = 0; tn < 4; ++tn)
#pragma unroll
      for (int r = 0; r < 4; ++r) {
        int rl = wm + tm * 16 + (lane >> 4) * 4 + r;
        if (rl < rowlim) {
          int col = n0 + wn + tn * 16 + fr;
          float g = accg[tm][tn][r];
          float u = accu[tm][tn][r];
          float s = g / (1.f + __expf(-g));
          Act[(size_t)(row0 + rl) * IDIM + col] = f2bf(s * u * sw[rl]);
        }
      }
}

// ------------------------------------------------------------ down GEMM ----
// 1-phase staging + XCD tile swizzle.
// Row stride 128B = 32 banks: without swizzle every row aliases (16-way!).
// Swizzle: logical 16B chunk q of row r at physical q ^ (r&7).
__global__ __launch_bounds__(256, 3) void down_kernel(
    const unsigned short* __restrict__ Act, const unsigned short* __restrict__ wdT,
    const int* __restrict__ hdr, const int* __restrict__ stok,
    float* __restrict__ out) {
  int bx = xcd_tile(blockIdx.x);       // m-tile fast, XCD-chunked
  int e = hdr[bx];
  if (e < 0) return;
  int row0 = hdr[64 + bx];
  int rowlim = hdr[128 + bx] - row0;
  int n0 = blockIdx.y * BN3;

  __shared__ __align__(16) unsigned short As[BM * BK3];   // 128 x 64
  __shared__ __align__(16) unsigned short Bd[BN3 * BK3];  // 64 x 64
  __shared__ int stk[BM];

  int tid = threadIdx.x, lane = tid & 63, wave = tid >> 6;
  if (tid < BM) stk[tid] = stok[row0 + tid];

  const unsigned short* wdb = wdT + (size_t)e * HDIM * IDIM;  // [H][I] bf16

  floatx4 acc[4][2];
  floatx4 zz = {0.f, 0.f, 0.f, 0.f};
#pragma unroll
  for (int a = 0; a < 4; ++a) { acc[a][0] = zz; acc[a][1] = zz; }

  int wm = (wave >> 1) * 64, wn = (wave & 1) * 32;
  int lr8 = lane >> 3;                         // row within 8-row chunk
  int lk8 = (((lane & 7) ^ lr8) * 8);          // swizzled global k-chunk
  int fr = lane & 15;
  int fk = fr & 7;                             // swizzle key on read

  for (int kb = 0; kb < IDIM; kb += BK3) {   // 44 iters
#pragma unroll
    for (int it = 0; it < 4; ++it) {
      int c = wave * 4 + it;     // 0..15, 8 rows each
      glds16(Act + (size_t)(row0 + c * 8 + lr8) * IDIM + kb + lk8, &As[c * 512]);
    }
#pragma unroll
    for (int it = 0; it < 2; ++it) {
      int c = wave * 2 + it;     // 0..7, 8 rows each
      glds16(wdb + (size_t)(n0 + c * 8 + lr8) * IDIM + kb + lk8, &Bd[c * 512]);
    }
    __syncthreads();

#pragma unroll
    for (int ks = 0; ks < BK3; ks += 32) {
      int q8 = (ks >> 3) + (lane >> 4);        // logical chunk 0..7
      int fo = ((q8 ^ fk) * 8);                // physical offset
      short8 af[4], bd8[2];
#pragma unroll
      for (int x = 0; x < 4; ++x)
        af[x] = *reinterpret_cast<const short8*>(&As[(wm + x * 16 + fr) * BK3 + fo]);
#pragma unroll
      for (int x = 0; x < 2; ++x)
        bd8[x] = *reinterpret_cast<const short8*>(&Bd[(wn + x * 16 + fr) * BK3 + fo]);
#pragma unroll
      for (int tm = 0; tm < 4; ++tm)
#pragma unroll
        for (int tn = 0; tn < 2; ++tn)
          acc[tm][tn] = __builtin_amdgcn_mfma_f32_16x16x32_bf16(af[tm], bd8[tn], acc[tm][tn], 0, 0, 0);
    }
    __syncthreads();
  }

#pragma unroll
  for (int tm = 0; tm < 4; ++tm)
#pragma unroll
    for (int tn = 0; tn < 2; ++tn)
#pragma unroll
      for (int r = 0; r < 4; ++r) {
        int rl = wm + tm * 16 + (lane >> 4) * 4 + r;
        if (rl < rowlim) {
          int col = n0 + wn + tn * 16 + fr;
          unsafeAtomicAdd(&out[(size_t)stk[rl] * HDIM + col], acc[tm][tn][r]);
        }
      }
}

// ======================== round-1 fallback kernels =========================
__global__ __launch_bounds__(512, 2) void gateup_fb(
    const unsigned short* __restrict__ Xs, const float* __restrict__ wg,
    const float* __restrict__ wu, const int* __restrict__ hdr,
    const float* __restrict__ sw_g, unsigned short* __restrict__ Act) {
  int by = blockIdx.y;
  int e = hdr[by];
  if (e < 0) return;
  int row0 = hdr[64 + by];
  int row_end = hdr[128 + by];
  int n0 = blockIdx.x * R1BN2;

  __shared__ __align__(16) unsigned short As[R1BM * R1BKp2];
  __shared__ __align__(16) unsigned short Bg[R1BN2 * R1BKp2];
  __shared__ __align__(16) unsigned short Bu[R1BN2 * R1BKp2];
  __shared__ float sw[R1BM];

  int tid = threadIdx.x, lane = tid & 63, wave = tid >> 6;
  if (tid < R1BM) sw[tid] = sw_g[row0 + tid];

  const float* wgb = wg + (size_t)e * HDIM * IDIM;
  const float* wub = wu + (size_t)e * HDIM * IDIM;

  floatx4 accg[4][4], accu[4][4];
  floatx4 zz = {0.f, 0.f, 0.f, 0.f};
#pragma unroll
  for (int a = 0; a < 4; ++a)
#pragma unroll
    for (int b = 0; b < 4; ++b) { accg[a][b] = zz; accu[a][b] = zz; }

  int wm = (wave >> 1) * 64, wn = (wave & 1) * 64;

  for (int kb = 0; kb < HDIM; kb += R1BK2) {
    __syncthreads();
#pragma unroll
    for (int it = 0; it < 2; ++it) {
      int cc = wave * 2 + it;
      int m = cc * 16 + (lane >> 2);
      int k = (lane & 3) * 8;
      uint4 v = *reinterpret_cast<const uint4*>(Xs + (size_t)(row0 + m) * HDIM + kb + k);
      *reinterpret_cast<uint4*>(&As[m * R1BKp2 + k]) = v;
    }
#pragma unroll
    for (int it = 0; it < 2; ++it) {
      int cc = wave * 2 + it;
      const float* wb = (cc & 8) ? wub : wgb;
      unsigned short* Bs = (cc & 8) ? Bu : Bg;
      int r = cc & 7;
      int kblk = r >> 1, nh = r & 1;
      int n = nh * 64 + lane;
      int k = kblk * 8;
      const float* src = wb + (size_t)(kb + k) * IDIM + n0 + n;
      uint4 q;
      q.x = f2bf(src[0])                | ((unsigned)f2bf(src[(size_t)IDIM])     << 16);
      q.y = f2bf(src[2 * (size_t)IDIM]) | ((unsigned)f2bf(src[3 * (size_t)IDIM]) << 16);
      q.z = f2bf(src[4 * (size_t)IDIM]) | ((unsigned)f2bf(src[5 * (size_t)IDIM]) << 16);
      q.w = f2bf(src[6 * (size_t)IDIM]) | ((unsigned)f2bf(src[7 * (size_t)IDIM]) << 16);
      *reinterpret_cast<uint4*>(&Bs[n * R1BKp2 + k]) = q;
    }
    __syncthreads();

    int krd = (lane >> 4) * 8;
    short8 af[4], bgf[4], buf_[4];
#pragma unroll
    for (int tm = 0; tm < 4; ++tm)
      af[tm] = *reinterpret_cast<const short8*>(&As[(wm + tm * 16 + (lane & 15)) * R1BKp2 + krd]);
#pragma unroll
    for (int tn = 0; tn < 4; ++tn) {
      bgf[tn]  = *reinterpret_cast<const short8*>(&Bg[(wn + tn * 16 + (lane & 15)) * R1BKp2 + krd]);
      buf_[tn] = *reinterpret_cast<const short8*>(&Bu[(wn + tn * 16 + (lane & 15)) * R1BKp2 + krd]);
    }
#pragma unroll
    for (int tm = 0; tm < 4; ++tm)
#pragma unroll
      for (int tn = 0; tn < 4; ++tn) {
        accg[tm][tn] = __builtin_amdgcn_mfma_f32_16x16x32_bf16(af[tm], bgf[tn], accg[tm][tn], 0, 0, 0);
        accu[tm][tn] = __builtin_amdgcn_mfma_f32_16x16x32_bf16(af[tm], buf_[tn], accu[tm][tn], 0, 0, 0);
      }
  }

  int rowlim = row_end - row0;
#pragma unroll
  for (int tm = 0; tm < 4; ++tm)
#pragma unroll
    for (int tn = 0; tn < 4; ++tn)
#pragma unroll
      for (int r = 0; r < 4; ++r) {
        int rl = wm + tm * 16 + (lane >> 4) * 4 + r;
        if (rl < rowlim) {
          int col = n0 + wn + tn * 16 + (lane & 15);
          float g = accg[tm][tn][r];
          float u = accu[tm][tn][r];
          float s = g / (1.f + __expf(-g));
          Act[(size_t)(row0 + rl) * IDIM + col] = f2bf(s * u * sw[rl]);
        }
      }
}

__global__ __launch_bounds__(512, 2) void down_fb(
    const unsigned short* __restrict__ Act, const float* __restrict__ wd,
    const int* __restrict__ hdr, const int* __restrict__ stok,
    float* __restrict__ out) {
  int by = blockIdx.y;
  int e = hdr[by];
  if (e < 0) return;
  int row0 = hdr[64 + by];
  int row_end = hdr[128 + by];
  int n0 = blockIdx.x * R1BN3;

  __shared__ __align__(16) unsigned short As[R1BM * R1BKp3];
  __shared__ __align__(16) unsigned short Bd[R1BN3 * R1BKp3];
  __shared__ int stk[R1BM];

  int tid = threadIdx.x, lane = tid & 63, wave = tid >> 6;
  if (tid < R1BM) stk[tid] = stok[row0 + tid];

  const float* wdb = wd + (size_t)e * IDIM * HDIM;

  floatx4 acc[4][2];
  floatx4 zz = {0.f, 0.f, 0.f, 0.f};
#pragma unroll
  for (int a = 0; a < 4; ++a) { acc[a][0] = zz; acc[a][1] = zz; }

  int wm = (wave >> 1) * 64, wn = (wave & 1) * 32;

  for (int kb = 0; kb < IDIM; kb += R1BK3) {
    __syncthreads();
#pragma unroll
    for (int it = 0; it < 4; ++it) {
      int cc = wave * 4 + it;
      int m = cc * 8 + (lane >> 3);
      int k = (lane & 7) * 8;
      uint4 v = *reinterpret_cast<const uint4*>(Act + (size_t)(row0 + m) * IDIM + kb + k);
      *reinterpret_cast<uint4*>(&As[m * R1BKp3 + k]) = v;
    }
    {
      int n = lane;
      int k = wave * 8;
      const float* src = wdb + (size_t)(kb + k) * HDIM + n0 + n;
      uint4 q;
      q.x = f2bf(src[0])        | ((unsigned)f2bf(src[HDIM])     << 16);
      q.y = f2bf(src[2 * HDIM]) | ((unsigned)f2bf(src[3 * HDIM]) << 16);
      q.z = f2bf(src[4 * HDIM]) | ((unsigned)f2bf(src[5 * HDIM]) << 16);
      q.w = f2bf(src[6 * HDIM]) | ((unsigned)f2bf(src[7 * HDIM]) << 16);
      *reinterpret_cast<uint4*>(&Bd[n * R1BKp3 + k]) = q;
    }
    __syncthreads();

#pragma unroll
    for (int ks = 0; ks < R1BK3; ks += 32) {
      int krd = ks + (lane >> 4) * 8;
      short8 af[4], bdf[2];
#pragma unroll
      for (int tm = 0; tm < 4; ++tm)
        af[tm] = *reinterpret_cast<const short8*>(&As[(wm + tm * 16 + (lane & 15)) * R1BKp3 + krd]);
#pragma unroll
      for (int tn = 0; tn < 2; ++tn)
        bdf[tn] = *reinterpret_cast<const short8*>(&Bd[(wn + tn * 16 + (lane & 15)) * R1BKp3 + krd]);
#pragma unroll
      for (int tm = 0; tm < 4; ++tm)
#pragma unroll
        for (int tn = 0; tn < 2; ++tn)
          acc[tm][tn] = __builtin_amdgcn_mfma_f32_16x16x32_bf16(af[tm], bdf[tn], acc[tm][tn], 0, 0, 0);
    }
  }

  int rowlim = row_end - row0;
#pragma unroll
  for (int tm = 0; tm < 4; ++tm)
#pragma unroll
    for (int tn = 0; tn < 2; ++tn)
#pragma unroll
      for (int r = 0; r < 4; ++r) {
        int rl = wm + tm * 16 + (lane >> 4) * 4 + r;
        if (rl < rowlim) {
          int col = n0 + wn + tn * 16 + (lane & 15);
          unsafeAtomicAdd(&out[(size_t)stk[rl] * HDIM + col], acc[tm][tn][r]);
        }
      }
}

// ---------------------------------------------------------------- launch ----
extern "C" void kernel_launch(void* const* d_in, const int* in_sizes, int n_in,
                              void* d_out, int out_size, void* d_ws, size_t ws_size,
                              hipStream_t stream) {
  const float* hidden = (const float*)d_in[0];
  const int* idx = (const int*)d_in[1];
  const float* vals = (const float*)d_in[2];
  const float* wg = (const float*)d_in[3];
  const float* wu = (const float*)d_in[4];
  const float* wd = (const float*)d_in[5];
  float* out = (float*)d_out;
  char* ws = (char*)d_ws;

  hipMemsetAsync(d_out, 0, (size_t)out_size * sizeof(float), stream);

  const size_t OFF_STOK = 4096;
  const size_t OFF_SW   = OFF_STOK + (size_t)NPP * 4;
  const size_t OFF_XS   = 65536;
  const size_t OFF_ACT  = OFF_XS + (size_t)NPP * HDIM * 2;
  const size_t OFF_WG   = OFF_ACT + (size_t)NPP * IDIM * 2;
  const size_t WSZ      = (size_t)NEXP * HDIM * IDIM * 2;   // 46.1 MB each
  const size_t OFF_WU   = OFF_WG + WSZ;
  const size_t OFF_WD   = OFF_WU + WSZ;
  const size_t NEED     = OFF_WD;          // aliased layout (wdT = wgT)
  const size_t NEED2    = OFF_WD + WSZ;    // non-aliased: wdT separate

  if (ws_size >= NEED) {
    int* hdr = (int*)ws;
    int* stok = (int*)(ws + OFF_STOK);
    float* sw = (float*)(ws + OFF_SW);
    unsigned short* Xs  = (unsigned short*)(ws + OFF_XS);
    unsigned short* Act = (unsigned short*)(ws + OFF_ACT);
    unsigned short* wgT = (unsigned short*)(ws + OFF_WG);
    unsigned short* wuT = (unsigned short*)(ws + OFF_WU);
    bool sep = (ws_size >= NEED2);
    unsigned short* wdT = sep ? (unsigned short*)(ws + OFF_WD) : wgT;

    setup_kernel<<<1, 1024, 0, stream>>>(idx, vals, hdr, stok, sw, BM);
    convert_kernel<<<dim3(704, NEXP, 2), 256, 0, stream>>>(wg, wu, wd, wgT, wuT, wdT, 0);
    gather_kernel<<<NPAIR, 256, 0, stream>>>(hidden, stok, Xs);
    if (sep) {
      // wd-convert fused as tail blocks of the gateup dispatch (wdT != wgT,
      // so the convert is independent of the GEMM's weight reads).
      gateup_kernel<<<GUB + CVB, 256, 0, stream>>>(Xs, wgT, wuT, hdr, sw, Act, wd, wdT);
    } else {
      gateup_kernel<<<GUB, 256, 0, stream>>>(Xs, wgT, wuT, hdr, sw, Act, wd, wdT);
      convert_kernel<<<dim3(704, NEXP, 1), 256, 0, stream>>>(wg, wu, wd, wgT, wuT, wdT, 2);
    }
    down_kernel<<<dim3(MAX_TILES, HDIM / BN3), 256, 0, stream>>>(Act, wdT, hdr, stok, out);
  } else {
    int* hdr = (int*)ws;
    int* stok = (int*)(ws + 4096);
    float* sw = (float*)(ws + 4096 + (size_t)R1NPP * 4);
    unsigned short* Xs  = (unsigned short*)(ws + 65536);
    unsigned short* Act = (unsigned short*)(ws + 65536 + (size_t)R1NPP * HDIM * 2);

    setup_kernel<<<1, 1024, 0, stream>>>(idx, vals, hdr, stok, sw, R1BM);
    gather_kernel<<<NPAIR, 256, 0, stream>>>(hidden, stok, Xs);
    gateup_fb<<<dim3(IDIM / R1BN2, R1T), 512, 0, stream>>>(Xs, wg, wu, hdr, sw, Act);
    down_fb<<<dim3(HDIM / R1BN3, R1T), 512, 0, stream>>>(Act, wd, hdr, stok, out);
  }
}

// Round 3
// 420.199 us; speedup vs baseline: 1.0753x; 1.0002x over previous
//
#include <hip/hip_runtime.h>
#include <stdint.h>

#define T_TOK 2048
#define KTOP  2
#define NEXP  8
#define HDIM  1024
#define IDIM  2816

#define NPAIR 4096

// ---- bf16 transposed-weight path ----
#define BM        128
#define MAX_TILES 40                // 8 XCDs x 5 tiles (swizzle relies on 40%8==0)
#define NPP       (NPAIR + BM)      // 4224
#define BN2       128               // gate/up N tile
#define BK2       32
#define BN3       128               // down N tile (round-3: was 64)
#define BK3       64
#define NYH       11                // gateup n-tiles per half (22 total)
#define GUBH      (MAX_TILES * NYH) // 440 GEMM blocks per half-dispatch
#define CVT       5632              // tail convert blocks (352*16 == 704*8)

// ---- fallback (round-1) path ----
#define R1BM   256
#define R1T    24
#define R1NPP  (NPAIR + R1BM)       // 4352
#define R1BN2  128
#define R1BK2  32
#define R1BKp2 40
#define R1BN3  64
#define R1BK3  64
#define R1BKp3 72

typedef __attribute__((ext_vector_type(8))) short short8;
typedef __attribute__((ext_vector_type(4))) float floatx4;

__device__ __forceinline__ unsigned short f2bf(float f) {
  unsigned int u = __float_as_uint(f);
  u += 0x7fffu + ((u >> 16) & 1u);   // round-to-nearest-even
  return (unsigned short)(u >> 16);
}

// HW packed f32->bf16 (RNE, matches f2bf): dst = {lo=bf16(a), hi=bf16(b)}
__device__ __forceinline__ unsigned int pkbf(float a, float b) {
  unsigned int r;
  asm volatile("v_cvt_pk_bf16_f32 %0, %1, %2" : "=v"(r) : "v"(a), "v"(b));
  return r;
}

__device__ __forceinline__ void glds16(const unsigned short* g, unsigned short* l) {
  __builtin_amdgcn_global_load_lds(
      (const __attribute__((address_space(1))) unsigned int*)g,
      (__attribute__((address_space(3))) unsigned int*)l, 16, 0, 0);
}

// XCD-chunked tile swizzle: with the m-tile index as the fast grid axis and
// the decode modulus a multiple of 8, XCD = mx % 8. Map so XCD k services
// contiguous tiles 5k..5k+4 -> one XCD touches ~1 expert's weight panels,
// which stay resident in its private 4MB L2.
__device__ __forceinline__ int xcd_tile(int bx0) {
  return (bx0 & 7) * (MAX_TILES / 8) + (bx0 >> 3);
}

// ---------------------------------------------------------------- setup ----
__global__ void setup_kernel(const int* __restrict__ idx,
                             const float* __restrict__ vals,
                             int* __restrict__ hdr,
                             int* __restrict__ stok,
                             float* __restrict__ sw, int bm) {
  __shared__ int cnt[NEXP];
  __shared__ int off[NEXP];
  int tid = threadIdx.x;
  if (tid < NEXP) cnt[tid] = 0;
  __syncthreads();
  for (int p = tid; p < NPAIR; p += blockDim.x) atomicAdd(&cnt[idx[p]], 1);
  __syncthreads();
  if (tid == 0) {
    int s = 0, nt = 0;
    for (int e = 0; e < NEXP; ++e) {
      off[e] = s;
      int n = cnt[e];
      for (int t0 = 0; t0 < n; t0 += bm) {
        hdr[nt] = e;
        hdr[64 + nt] = s + t0;
        hdr[128 + nt] = s + n;
        nt++;
      }
      s += n;
    }
    for (; nt < 64; ++nt) hdr[nt] = -1;
  }
  __syncthreads();
  for (int p = tid; p < NPAIR; p += blockDim.x) {
    int e = idx[p];
    int pos = atomicAdd(&off[e], 1);
    stok[pos] = p / KTOP;
    sw[pos] = vals[p];
  }
}

// --------------------------------------------------------------- gather ----
__global__ void gather_kernel(const float* __restrict__ hidden,
                              const int* __restrict__ stok,
                              unsigned short* __restrict__ Xs) {
  int p = blockIdx.x;
  int t = stok[p];
  const float4* src = reinterpret_cast<const float4*>(hidden + (size_t)t * HDIM);
  float4 v = src[threadIdx.x];
  uint2 q;
  q.x = pkbf(v.x, v.y);
  q.y = pkbf(v.z, v.w);
  *reinterpret_cast<uint2*>(Xs + (size_t)p * HDIM + threadIdx.x * 4) = q;
}

// ----------------------------------------------- weight convert+transpose --
// fp32 [e][M][N] -> bf16 [e][N][M].  z (+zoff): 0=wg, 1=wu, 2=wd.
// ioff/intx: N-tile window (intx tiles starting at column tile ioff).
__global__ __launch_bounds__(256) void convert_kernel(
    const float* __restrict__ wg, const float* __restrict__ wu,
    const float* __restrict__ wd, unsigned short* __restrict__ wgT,
    unsigned short* __restrict__ wuT, unsigned short* __restrict__ wdT,
    int zoff, int ioff, int intx) {
  __shared__ float ls[64][65];
  int z = blockIdx.z + zoff;
  int e = blockIdx.y;
  int M = (z == 2) ? IDIM : HDIM;
  int N = (z == 2) ? HDIM : IDIM;
  const float* src = (z == 0 ? wg : z == 1 ? wu : wd) + (size_t)e * M * N;
  unsigned short* dst = (z == 0 ? wgT : z == 1 ? wuT : wdT) + (size_t)e * M * N;
  int n0 = ((blockIdx.x % intx) + ioff) << 6;
  int m0 = (blockIdx.x / intx) << 6;
  int t = threadIdx.x;
  int rr = t >> 4, cc = (t & 15) * 4;
#pragma unroll
  for (int i = 0; i < 4; ++i) {
    int r = rr + i * 16;
    float4 v = *reinterpret_cast<const float4*>(src + (size_t)(m0 + r) * N + n0 + cc);
    ls[r][cc] = v.x; ls[r][cc + 1] = v.y; ls[r][cc + 2] = v.z; ls[r][cc + 3] = v.w;
  }
  __syncthreads();
  int mc = (t & 7) * 8, nn = t >> 3;   // 8 lanes per output row, 16B/lane
#pragma unroll
  for (int i = 0; i < 2; ++i) {
    int n = nn + i * 32;
    uint4 q;
    q.x = pkbf(ls[mc][n],     ls[mc + 1][n]);
    q.y = pkbf(ls[mc + 2][n], ls[mc + 3][n]);
    q.z = pkbf(ls[mc + 4][n], ls[mc + 5][n]);
    q.w = pkbf(ls[mc + 6][n], ls[mc + 7][n]);
    *reinterpret_cast<uint4*>(dst + (size_t)(n0 + n) * M + m0 + mc) = q;
  }
}

// -------------------------------------------------- fused gate+up GEMM ----
// Split into two n-half dispatches (mode 0: n-tiles 0..10, mode 1: 11..21).
// Each half uses only 440 GEMM blocks (~110 CUs at 4 blocks/CU), so tail
// convert blocks run CONCURRENTLY on the remaining CUs:
//   mode 0 tail: convert wg/wu fp32->bf16T for the n-half2 columns
//                (disjoint wgT/wuT rows from what the GEMM reads -> no race)
//   mode 1 tail: convert wd -> wdT (consumed by the following down kernel)
// LDS k-chunk XOR swizzle: logical 16B chunk q of row r lives at physical
// chunk q ^ ((r>>1)&3)  (row stride 64B = 16 banks -> 2-way max aliasing).
__global__ __launch_bounds__(256, 2) void gateup_kernel(
    const unsigned short* __restrict__ Xs, const unsigned short* __restrict__ wgT,
    const unsigned short* __restrict__ wuT, const int* __restrict__ hdr,
    const float* __restrict__ sw_g, unsigned short* __restrict__ Act,
    const float* __restrict__ wg, const float* __restrict__ wu,
    const float* __restrict__ wd, unsigned short* __restrict__ wgTw,
    unsigned short* __restrict__ wuTw, unsigned short* __restrict__ wdTw,
    int mode) {
  __shared__ __align__(16) char smem[25088];

  if (blockIdx.x >= GUBH) {
    // ---- convert tail block ----
    int cb = blockIdx.x - GUBH;          // 0..CVT-1
    const float* src;
    unsigned short* dst;
    int n0, m0, rdN, wrM;
    if (mode == 0) {
      // wg/wu half2: fp32 [e][H][I] cols [1408,2816) -> bf16 [e][I][H]
      int z = cb / 2816;                 // 2816 = 352*NEXP
      int rem = cb - z * 2816;
      int e = rem / 352;
      int bq = rem % 352;                // 22 i-tiles x 16 h-tiles
      n0 = ((bq % 22) + 22) << 6;        // i in [1408, 2816)
      m0 = (bq / 22) << 6;               // h
      rdN = IDIM; wrM = HDIM;
      src = (z ? wu : wg) + (size_t)e * HDIM * IDIM;
      dst = (z ? wuTw : wgTw) + (size_t)e * IDIM * HDIM;
    } else {
      // wd: fp32 [e][I][H] -> bf16 [e][H][I]
      int e = cb / 704;                  // 704 = 16 h-tiles x 44 i-tiles
      int bq = cb % 704;
      n0 = (bq % 16) << 6;               // h
      m0 = (bq / 16) << 6;               // i
      rdN = HDIM; wrM = IDIM;
      src = wd + (size_t)e * IDIM * HDIM;
      dst = wdTw + (size_t)e * IDIM * HDIM;
    }
    float (*ls)[65] = reinterpret_cast<float(*)[65]>(smem);
    int t = threadIdx.x;
    int rr = t >> 4, cc = (t & 15) * 4;
#pragma unroll
    for (int i = 0; i < 4; ++i) {
      int r = rr + i * 16;
      float4 v = *reinterpret_cast<const float4*>(src + (size_t)(m0 + r) * rdN + n0 + cc);
      ls[r][cc] = v.x; ls[r][cc + 1] = v.y; ls[r][cc + 2] = v.z; ls[r][cc + 3] = v.w;
    }
    __syncthreads();
    int mc = (t & 7) * 8, nn = t >> 3;
#pragma unroll
    for (int i = 0; i < 2; ++i) {
      int n = nn + i * 32;
      uint4 q;
      q.x = pkbf(ls[mc][n],     ls[mc + 1][n]);
      q.y = pkbf(ls[mc + 2][n], ls[mc + 3][n]);
      q.z = pkbf(ls[mc + 4][n], ls[mc + 5][n]);
      q.w = pkbf(ls[mc + 6][n], ls[mc + 7][n]);
      *reinterpret_cast<uint4*>(dst + (size_t)(n0 + n) * wrM + m0 + mc) = q;
    }
    return;
  }

  // ---- gateup GEMM block ----
  int mx = blockIdx.x % MAX_TILES;     // fast axis -> XCD = mx % 8
  int ny = blockIdx.x / MAX_TILES + mode * NYH;
  int bx = xcd_tile(mx);
  int e = hdr[bx];
  if (e < 0) return;
  int row0 = hdr[64 + bx];
  int rowlim = hdr[128 + bx] - row0;
  int n0 = ny * BN2;

  unsigned short* As = reinterpret_cast<unsigned short*>(smem);          // 8KB
  unsigned short* Bg = reinterpret_cast<unsigned short*>(smem + 8192);   // 8KB
  unsigned short* Bu = reinterpret_cast<unsigned short*>(smem + 16384);  // 8KB
  float* sw = reinterpret_cast<float*>(smem + 24576);                    // 512B

  int tid = threadIdx.x, lane = tid & 63, wave = tid >> 6;
  if (tid < BM) sw[tid] = sw_g[row0 + tid];

  const unsigned short* wgb = wgT + (size_t)e * IDIM * HDIM;  // [I][H] bf16
  const unsigned short* wub = wuT + (size_t)e * IDIM * HDIM;

  floatx4 accg[4][4], accu[4][4];
  floatx4 zz = {0.f, 0.f, 0.f, 0.f};
#pragma unroll
  for (int a = 0; a < 4; ++a)
#pragma unroll
    for (int b = 0; b < 4; ++b) { accg[a][b] = zz; accu[a][b] = zz; }

  int wm = (wave >> 1) * 64, wn = (wave & 1) * 64;
  int lr = lane >> 2;                        // row within 16-row chunk
  int lk = (((lane & 3) ^ ((lr >> 1) & 3)) * 8);   // swizzled global k-chunk
  int fr = lane & 15;
  int fq = (((lane >> 4) ^ ((fr >> 1) & 3)) * 8);  // swizzled read offset

  for (int kb = 0; kb < HDIM; kb += BK2) {
#pragma unroll
    for (int it = 0; it < 2; ++it) {
      int c = wave * 2 + it;     // 0..7, 16 rows each
      glds16(Xs  + (size_t)(row0 + c * 16 + lr) * HDIM + kb + lk, &As[c * 512]);
      glds16(wgb + (size_t)(n0  + c * 16 + lr) * HDIM + kb + lk, &Bg[c * 512]);
      glds16(wub + (size_t)(n0  + c * 16 + lr) * HDIM + kb + lk, &Bu[c * 512]);
    }
    __syncthreads();

    short8 af[4], bg8[4], bu8[4];
#pragma unroll
    for (int x = 0; x < 4; ++x) {
      af[x]  = *reinterpret_cast<const short8*>(&As[(wm + x * 16 + fr) * BK2 + fq]);
      bg8[x] = *reinterpret_cast<const short8*>(&Bg[(wn + x * 16 + fr) * BK2 + fq]);
      bu8[x] = *reinterpret_cast<const short8*>(&Bu[(wn + x * 16 + fr) * BK2 + fq]);
    }
#pragma unroll
    for (int tm = 0; tm < 4; ++tm)
#pragma unroll
      for (int tn = 0; tn < 4; ++tn) {
        accg[tm][tn] = __builtin_amdgcn_mfma_f32_16x16x32_bf16(af[tm], bg8[tn], accg[tm][tn], 0, 0, 0);
        accu[tm][tn] = __builtin_amdgcn_mfma_f32_16x16x32_bf16(af[tm], bu8[tn], accu[tm][tn], 0, 0, 0);
      }
    __syncthreads();
  }

#pragma unroll
  for (int tm = 0; tm < 4; ++tm)
#pragma unroll
    for (int tn = 0; tn < 4; ++tn)
#pragma unroll
      for (int r = 0; r < 4; ++r) {
        int rl = wm + tm * 16 + (lane >> 4) * 4 + r;
        if (rl < rowlim) {
          int col = n0 + wn + tn * 16 + fr;
          float g = accg[tm][tn][r];
          float u = accu[tm][tn][r];
          float s = g / (1.f + __expf(-g));
          Act[(size_t)(row0 + rl) * IDIM + col] = f2bf(s * u * sw[rl]);
        }
      }
}

// ------------------------------------------------------------ down GEMM ----
// Round-3: BN3=128 (acc 4x4, 2x arithmetic intensity per staged byte) with
// K-split of 2 (grid 40x8x2 = 640 blocks, balanced ~2.5 blocks/CU-slot;
// partial K-sums merge through the existing atomicAdd epilogue).
// Row stride 128B = 32 banks: swizzle logical 16B chunk q of row r to
// physical q ^ (r&7); staging writes with the inverse pre-swizzled source.
__global__ __launch_bounds__(256, 4) void down_kernel(
    const unsigned short* __restrict__ Act, const unsigned short* __restrict__ wdT,
    const int* __restrict__ hdr, const int* __restrict__ stok,
    float* __restrict__ out) {
  int bx = xcd_tile(blockIdx.x);       // m-tile fast, XCD-chunked
  int e = hdr[bx];
  if (e < 0) return;
  int row0 = hdr[64 + bx];
  int rowlim = hdr[128 + bx] - row0;
  int n0 = blockIdx.y * BN3;
  int kb0 = blockIdx.z * (IDIM / 2);   // K-split half: 1408 = 22 x BK3
  int kend = kb0 + (IDIM / 2);

  __shared__ __align__(16) unsigned short As[BM * BK3];    // 128 x 64 = 16KB
  __shared__ __align__(16) unsigned short Bd[BN3 * BK3];   // 128 x 64 = 16KB
  __shared__ int stk[BM];

  int tid = threadIdx.x, lane = tid & 63, wave = tid >> 6;
  if (tid < BM) stk[tid] = stok[row0 + tid];

  const unsigned short* wdb = wdT + (size_t)e * HDIM * IDIM;  // [H][I] bf16

  floatx4 acc[4][4];
  floatx4 zz = {0.f, 0.f, 0.f, 0.f};
#pragma unroll
  for (int a = 0; a < 4; ++a)
#pragma unroll
    for (int b = 0; b < 4; ++b) acc[a][b] = zz;

  int wm = (wave >> 1) * 64, wn = (wave & 1) * 64;
  int lr8 = lane >> 3;                         // row within 8-row chunk
  int lk8 = (((lane & 7) ^ lr8) * 8);          // swizzled global k-chunk
  int fr = lane & 15;
  int fk = fr & 7;                             // swizzle key on read

  for (int kb = kb0; kb < kend; kb += BK3) {   // 22 iters
#pragma unroll
    for (int it = 0; it < 4; ++it) {
      int c = wave * 4 + it;     // 0..15, 8 rows each
      glds16(Act + (size_t)(row0 + c * 8 + lr8) * IDIM + kb + lk8, &As[c * 512]);
      glds16(wdb + (size_t)(n0  + c * 8 + lr8) * IDIM + kb + lk8, &Bd[c * 512]);
    }
    __syncthreads();

#pragma unroll
    for (int ks = 0; ks < BK3; ks += 32) {
      int q8 = (ks >> 3) + (lane >> 4);        // logical chunk 0..7
      int fo = ((q8 ^ fk) * 8);                // physical offset
      short8 af[4], bd8[4];
#pragma unroll
      for (int x = 0; x < 4; ++x) {
        af[x]  = *reinterpret_cast<const short8*>(&As[(wm + x * 16 + fr) * BK3 + fo]);
        bd8[x] = *reinterpret_cast<const short8*>(&Bd[(wn + x * 16 + fr) * BK3 + fo]);
      }
#pragma unroll
      for (int tm = 0; tm < 4; ++tm)
#pragma unroll
        for (int tn = 0; tn < 4; ++tn)
          acc[tm][tn] = __builtin_amdgcn_mfma_f32_16x16x32_bf16(af[tm], bd8[tn], acc[tm][tn], 0, 0, 0);
    }
    __syncthreads();
  }

#pragma unroll
  for (int tm = 0; tm < 4; ++tm)
#pragma unroll
    for (int tn = 0; tn < 4; ++tn)
#pragma unroll
      for (int r = 0; r < 4; ++r) {
        int rl = wm + tm * 16 + (lane >> 4) * 4 + r;
        if (rl < rowlim) {
          int col = n0 + wn + tn * 16 + fr;
          unsafeAtomicAdd(&out[(size_t)stk[rl] * HDIM + col], acc[tm][tn][r]);
        }
      }
}

// ======================== round-1 fallback kernels =========================
__global__ __launch_bounds__(512, 2) void gateup_fb(
    const unsigned short* __restrict__ Xs, const float* __restrict__ wg,
    const float* __restrict__ wu, const int* __restrict__ hdr,
    const float* __restrict__ sw_g, unsigned short* __restrict__ Act) {
  int by = blockIdx.y;
  int e = hdr[by];
  if (e < 0) return;
  int row0 = hdr[64 + by];
  int row_end = hdr[128 + by];
  int n0 = blockIdx.x * R1BN2;

  __shared__ __align__(16) unsigned short As[R1BM * R1BKp2];
  __shared__ __align__(16) unsigned short Bg[R1BN2 * R1BKp2];
  __shared__ __align__(16) unsigned short Bu[R1BN2 * R1BKp2];
  __shared__ float sw[R1BM];

  int tid = threadIdx.x, lane = tid & 63, wave = tid >> 6;
  if (tid < R1BM) sw[tid] = sw_g[row0 + tid];

  const float* wgb = wg + (size_t)e * HDIM * IDIM;
  const float* wub = wu + (size_t)e * HDIM * IDIM;

  floatx4 accg[4][4], accu[4][4];
  floatx4 zz = {0.f, 0.f, 0.f, 0.f};
#pragma unroll
  for (int a = 0; a < 4; ++a)
#pragma unroll
    for (int b = 0; b < 4; ++b) { accg[a][b] = zz; accu[a][b] = zz; }

  int wm = (wave >> 1) * 64, wn = (wave & 1) * 64;

  for (int kb = 0; kb < HDIM; kb += R1BK2) {
    __syncthreads();
#pragma unroll
    for (int it = 0; it < 2; ++it) {
      int cc = wave * 2 + it;
      int m = cc * 16 + (lane >> 2);
      int k = (lane & 3) * 8;
      uint4 v = *reinterpret_cast<const uint4*>(Xs + (size_t)(row0 + m) * HDIM + kb + k);
      *reinterpret_cast<uint4*>(&As[m * R1BKp2 + k]) = v;
    }
#pragma unroll
    for (int it = 0; it < 2; ++it) {
      int cc = wave * 2 + it;
      const float* wb = (cc & 8) ? wub : wgb;
      unsigned short* Bs = (cc & 8) ? Bu : Bg;
      int r = cc & 7;
      int kblk = r >> 1, nh = r & 1;
      int n = nh * 64 + lane;
      int k = kblk * 8;
      const float* src = wb + (size_t)(kb + k) * IDIM + n0 + n;
      uint4 q;
      q.x = f2bf(src[0])                | ((unsigned)f2bf(src[(size_t)IDIM])     << 16);
      q.y = f2bf(src[2 * (size_t)IDIM]) | ((unsigned)f2bf(src[3 * (size_t)IDIM]) << 16);
      q.z = f2bf(src[4 * (size_t)IDIM]) | ((unsigned)f2bf(src[5 * (size_t)IDIM]) << 16);
      q.w = f2bf(src[6 * (size_t)IDIM]) | ((unsigned)f2bf(src[7 * (size_t)IDIM]) << 16);
      *reinterpret_cast<uint4*>(&Bs[n * R1BKp2 + k]) = q;
    }
    __syncthreads();

    int krd = (lane >> 4) * 8;
    short8 af[4], bgf[4], buf_[4];
#pragma unroll
    for (int tm = 0; tm < 4; ++tm)
      af[tm] = *reinterpret_cast<const short8*>(&As[(wm + tm * 16 + (lane & 15)) * R1BKp2 + krd]);
#pragma unroll
    for (int tn = 0; tn < 4; ++tn) {
      bgf[tn]  = *reinterpret_cast<const short8*>(&Bg[(wn + tn * 16 + (lane & 15)) * R1BKp2 + krd]);
      buf_[tn] = *reinterpret_cast<const short8*>(&Bu[(wn + tn * 16 + (lane & 15)) * R1BKp2 + krd]);
    }
#pragma unroll
    for (int tm = 0; tm < 4; ++tm)
#pragma unroll
      for (int tn = 0; tn < 4; ++tn) {
        accg[tm][tn] = __builtin_amdgcn_mfma_f32_16x16x32_bf16(af[tm], bgf[tn], accg[tm][tn], 0, 0, 0);
        accu[tm][tn] = __builtin_amdgcn_mfma_f32_16x16x32_bf16(af[tm], buf_[tn], accu[tm][tn], 0, 0, 0);
      }
  }

  int rowlim = row_end - row0;
#pragma unroll
  for (int tm = 0; tm < 4; ++tm)
#pragma unroll
    for (int tn = 0; tn < 4; ++tn)
#pragma unroll
      for (int r = 0; r < 4; ++r) {
        int rl = wm + tm * 16 + (lane >> 4) * 4 + r;
        if (rl < rowlim) {
          int col = n0 + wn + tn * 16 + (lane & 15);
          float g = accg[tm][tn][r];
          float u = accu[tm][tn][r];
          float s = g / (1.f + __expf(-g));
          Act[(size_t)(row0 + rl) * IDIM + col] = f2bf(s * u * sw[rl]);
        }
      }
}

__global__ __launch_bounds__(512, 2) void down_fb(
    const unsigned short* __restrict__ Act, const float* __restrict__ wd,
    const int* __restrict__ hdr, const int* __restrict__ stok,
    float* __restrict__ out) {
  int by = blockIdx.y;
  int e = hdr[by];
  if (e < 0) return;
  int row0 = hdr[64 + by];
  int row_end = hdr[128 + by];
  int n0 = blockIdx.x * R1BN3;

  __shared__ __align__(16) unsigned short As[R1BM * R1BKp3];
  __shared__ __align__(16) unsigned short Bd[R1BN3 * R1BKp3];
  __shared__ int stk[R1BM];

  int tid = threadIdx.x, lane = tid & 63, wave = tid >> 6;
  if (tid < R1BM) stk[tid] = stok[row0 + tid];

  const float* wdb = wd + (size_t)e * IDIM * HDIM;

  floatx4 acc[4][2];
  floatx4 zz = {0.f, 0.f, 0.f, 0.f};
#pragma unroll
  for (int a = 0; a < 4; ++a) { acc[a][0] = zz; acc[a][1] = zz; }

  int wm = (wave >> 1) * 64, wn = (wave & 1) * 32;

  for (int kb = 0; kb < IDIM; kb += R1BK3) {
    __syncthreads();
#pragma unroll
    for (int it = 0; it < 4; ++it) {
      int cc = wave * 4 + it;
      int m = cc * 8 + (lane >> 3);
      int k = (lane & 7) * 8;
      uint4 v = *reinterpret_cast<const uint4*>(Act + (size_t)(row0 + m) * IDIM + kb + k);
      *reinterpret_cast<uint4*>(&As[m * R1BKp3 + k]) = v;
    }
    {
      int n = lane;
      int k = wave * 8;
      const float* src = wdb + (size_t)(kb + k) * HDIM + n0 + n;
      uint4 q;
      q.x = f2bf(src[0])        | ((unsigned)f2bf(src[HDIM])     << 16);
      q.y = f2bf(src[2 * HDIM]) | ((unsigned)f2bf(src[3 * HDIM]) << 16);
      q.z = f2bf(src[4 * HDIM]) | ((unsigned)f2bf(src[5 * HDIM]) << 16);
      q.w = f2bf(src[6 * HDIM]) | ((unsigned)f2bf(src[7 * HDIM]) << 16);
      *reinterpret_cast<uint4*>(&Bd[n * R1BKp3 + k]) = q;
    }
    __syncthreads();

#pragma unroll
    for (int ks = 0; ks < R1BK3; ks += 32) {
      int krd = ks + (lane >> 4) * 8;
      short8 af[4], bdf[2];
#pragma unroll
      for (int tm = 0; tm < 4; ++tm)
        af[tm] = *reinterpret_cast<const short8*>(&As[(wm + tm * 16 + (lane & 15)) * R1BKp3 + krd]);
#pragma unroll
      for (int tn = 0; tn < 2; ++tn)
        bdf[tn] = *reinterpret_cast<const short8*>(&Bd[(wn + tn * 16 + (lane & 15)) * R1BKp3 + krd]);
#pragma unroll
      for (int tm = 0; tm < 4; ++tm)
#pragma unroll
        for (int tn = 0; tn < 2; ++tn)
          acc[tm][tn] = __builtin_amdgcn_mfma_f32_16x16x32_bf16(af[tm], bdf[tn], acc[tm][tn], 0, 0, 0);
    }
  }

  int rowlim = row_end - row0;
#pragma unroll
  for (int tm = 0; tm < 4; ++tm)
#pragma unroll
    for (int tn = 0; tn < 2; ++tn)
#pragma unroll
      for (int r = 0; r < 4; ++r) {
        int rl = wm + tm * 16 + (lane >> 4) * 4 + r;
        if (rl < rowlim) {
          int col = n0 + wn + tn * 16 + (lane & 15);
          unsafeAtomicAdd(&out[(size_t)stk[rl] * HDIM + col], acc[tm][tn][r]);
        }
      }
}

// ---------------------------------------------------------------- launch ----
extern "C" void kernel_launch(void* const* d_in, const int* in_sizes, int n_in,
                              void* d_out, int out_size, void* d_ws, size_t ws_size,
                              hipStream_t stream) {
  const float* hidden = (const float*)d_in[0];
  const int* idx = (const int*)d_in[1];
  const float* vals = (const float*)d_in[2];
  const float* wg = (const float*)d_in[3];
  const float* wu = (const float*)d_in[4];
  const float* wd = (const float*)d_in[5];
  float* out = (float*)d_out;
  char* ws = (char*)d_ws;

  hipMemsetAsync(d_out, 0, (size_t)out_size * sizeof(float), stream);

  const size_t OFF_STOK = 4096;
  const size_t OFF_SW   = OFF_STOK + (size_t)NPP * 4;
  const size_t OFF_XS   = 65536;
  const size_t OFF_ACT  = OFF_XS + (size_t)NPP * HDIM * 2;
  const size_t OFF_WG   = OFF_ACT + (size_t)NPP * IDIM * 2;
  const size_t WSZ      = (size_t)NEXP * HDIM * IDIM * 2;   // 46.1 MB each
  const size_t OFF_WU   = OFF_WG + WSZ;
  const size_t OFF_WD   = OFF_WU + WSZ;
  const size_t NEED     = OFF_WD;          // aliased layout (wdT = wgT)
  const size_t NEED2    = OFF_WD + WSZ;    // non-aliased: wdT separate

  if (ws_size >= NEED) {
    int* hdr = (int*)ws;
    int* stok = (int*)(ws + OFF_STOK);
    float* sw = (float*)(ws + OFF_SW);
    unsigned short* Xs  = (unsigned short*)(ws + OFF_XS);
    unsigned short* Act = (unsigned short*)(ws + OFF_ACT);
    unsigned short* wgT = (unsigned short*)(ws + OFF_WG);
    unsigned short* wuT = (unsigned short*)(ws + OFF_WU);
    bool sep = (ws_size >= NEED2);
    unsigned short* wdT = sep ? (unsigned short*)(ws + OFF_WD) : wgT;

    setup_kernel<<<1, 1024, 0, stream>>>(idx, vals, hdr, stok, sw, BM);
    // convert wg/wu half1 (i-cols [0,1408)) only; half2 rides in D2's tail.
    convert_kernel<<<dim3(352, NEXP, 2), 256, 0, stream>>>(
        wg, wu, wd, wgT, wuT, wdT, 0, 0, 22);
    gather_kernel<<<NPAIR, 256, 0, stream>>>(hidden, stok, Xs);
    // D2: gateup n-half1 + tail converts wg/wu half2 (disjoint wgT/wuT rows).
    gateup_kernel<<<GUBH + CVT, 256, 0, stream>>>(
        Xs, wgT, wuT, hdr, sw, Act, wg, wu, wd, wgT, wuT, wdT, 0);
    if (sep) {
      // D3: gateup n-half2 + tail converts wd -> wdT (separate buffer).
      gateup_kernel<<<GUBH + CVT, 256, 0, stream>>>(
          Xs, wgT, wuT, hdr, sw, Act, wg, wu, wd, wgT, wuT, wdT, 1);
    } else {
      // aliased wdT==wgT: no tail (would clobber wgT mid-read); serial z2.
      gateup_kernel<<<GUBH, 256, 0, stream>>>(
          Xs, wgT, wuT, hdr, sw, Act, wg, wu, wd, wgT, wuT, wdT, 1);
      convert_kernel<<<dim3(704, NEXP, 1), 256, 0, stream>>>(
          wg, wu, wd, wgT, wuT, wdT, 2, 0, 16);
    }
    down_kernel<<<dim3(MAX_TILES, HDIM / BN3, 2), 256, 0, stream>>>(
        Act, wdT, hdr, stok, out);
  } else {
    int* hdr = (int*)ws;
    int* stok = (int*)(ws + 4096);
    float* sw = (float*)(ws + 4096 + (size_t)R1NPP * 4);
    unsigned short* Xs  = (unsigned short*)(ws + 65536);
    unsigned short* Act = (unsigned short*)(ws + 65536 + (size_t)R1NPP * HDIM * 2);

    setup_kernel<<<1, 1024, 0, stream>>>(idx, vals, hdr, stok, sw, R1BM);
    gather_kernel<<<NPAIR, 256, 0, stream>>>(hidden, stok, Xs);
    gateup_fb<<<dim3(IDIM / R1BN2, R1T), 512, 0, stream>>>(Xs, wg, wu, hdr, sw, Act);
    down_fb<<<dim3(HDIM / R1BN3, R1T), 512, 0, stream>>>(Act, wd, hdr, stok, out);
  }
}